// Round 7
// baseline (1391.788 us; speedup 1.0000x reference)
//
#include <hip/hip_runtime.h>

// Problem dims (fixed by setup_inputs)
#define B_  4
#define L_  2048
#define D_  2048
#define R_  2560
#define BL_ (B_ * L_)
#define LP_ (L_ + 6)          // padded L for conv shifts (3 each side)

#define CHK_  16              // scan chunks along L
#define CLEN_ (L_ / CHK_)     // 128

typedef unsigned short u16;
typedef unsigned int   u32;

typedef __attribute__((ext_vector_type(8))) short short8;
typedef __attribute__((ext_vector_type(4))) float f32x4;

static __device__ __forceinline__ u16 f2bf(float f) {
  u32 x = __float_as_uint(f);
  x += 0x7fffu + ((x >> 16) & 1u);   // round-to-nearest-even
  return (u16)(x >> 16);
}
static __device__ __forceinline__ float bf2f(u16 u) {
  return __uint_as_float(((u32)u) << 16);
}

// async global->LDS, 16B per lane; LDS dest = wave-uniform base + lane*16
static __device__ __forceinline__ void gld16(const u16* g, u16* l) {
  __builtin_amdgcn_global_load_lds(
      (const __attribute__((address_space(1))) void*)g,
      (__attribute__((address_space(3))) void*)l, 16, 0, 0);
}

#define SB0()     __builtin_amdgcn_sched_barrier(0)
#define BAR()     __builtin_amdgcn_s_barrier()
#define LGKM0()   do { asm volatile("s_waitcnt lgkmcnt(0)" ::: "memory"); SB0(); } while (0)

// ---------------- conversions ----------------
__global__ void cvt_bf16(const float* __restrict__ src, u16* __restrict__ dst, int n) {
  int i = blockIdx.x * blockDim.x + threadIdx.x;
  int stride = gridDim.x * blockDim.x;
  for (; i < n; i += stride) dst[i] = f2bf(src[i]);
}

// conv_w [R,R,4] fp32 -> 4 planes of [R,R] bf16 (tap-major)
__global__ void cvt_convw(const float* __restrict__ cw, u16* __restrict__ out) {
  int i = blockIdx.x * blockDim.x + threadIdx.x;  // over R_*R_ (o*R + iin)
  if (i >= R_ * R_) return;
  const float4 v = *(const float4*)(cw + (size_t)i * 4);
  out[(size_t)0 * R_ * R_ + i] = f2bf(v.x);
  out[(size_t)1 * R_ * R_ + i] = f2bf(v.y);
  out[(size_t)2 * R_ * R_ + i] = f2bf(v.z);
  out[(size_t)3 * R_ * R_ + i] = f2bf(v.w);
}

// zero the 3+3 pad rows per batch of padded h1 [B][LP_][R]
__global__ void zero_pads(u16* __restrict__ h1p) {
  int i = blockIdx.x * blockDim.x + threadIdx.x;   // over 24*R_
  if (i >= 24 * R_) return;
  const int rr = i / R_, c = i % R_;
  const int b = rr / 6, k = rr % 6;
  const int row = b * LP_ + (k < 3 ? k : L_ + k);  // rows 0..2 and 2051..2053
  h1p[(size_t)row * R_ + c] = 0;
}

// concat gate biases [ba | bx] -> bcat[2R]
__global__ void cat_bias(const float* __restrict__ ba, const float* __restrict__ bx,
                         float* __restrict__ bcat) {
  int i = blockIdx.x * blockDim.x + threadIdx.x;
  if (i < R_) bcat[i] = ba[i];
  else if (i < 2 * R_) bcat[i] = bx[i - R_];
}

// ---------------- 128x128 pipelined 4-phase GEMM, 2 WGs/CU ----------------
// C[M, N] = act(A[M,K] * Bm[N,K]^T + bias[N]), bf16 in, fp32 accum.
// BM=BN=128, BK=64. 256 threads = 4 waves (2M x 2N). Per wave 64x64 = acc[4][4]
// (64 AGPRs). LDS = 2 x (A 16KB + B 16KB) = 64 KB -> TWO WGs per CU (the r5 512-thread
// 256^2 kernel had 128 KB LDS = 1 WG/CU: in-round MfmaUtil ~51% because the serial
// [ds_read; BAR; lgkmcnt0; MFMA] phase had nothing to overlap with). 2 WGs give
// m97/m114-style cross-WG overlap: one WG's MFMA covers the other's LDS/stage/barrier.
// Register budget (unified file, 2 waves/SIMD = 256/wave): acc 64 + arch ~110 -> safe.
//
// r6 BUG (absmax 98.6): stB's src included srow AND the issue loop added (s*32+srow)
// again -> staged B rows bn+c*64+s*32+2*srow. Fixed: srow only in the loop term
// (matching stA). Everything else identical to r6.
//
// Schedule logic IDENTICAL to r5 (proven, 0 bank conflicts, no spill):
//   ph0: ds_read A(h0,k0)+B(k0)->bF; stage A1(t+1)->lds[p^1].h1 (2 iss); BAR;LGKM0;
//        MFMA acc[0..1]
//   ph1: ds_read A(h1,k0)                                              ; BAR;LGKM0;
//        MFMA acc[2..3]
//   ph2: ds_read A(h0,k1)+B(k1)->bF                                    ; BAR;LGKM0;
//        MFMA acc[0..1]
//   ph3: ds_read A(h1,k1); stage A0(t+2)+B01(t+2)->lds[p] (6 iss)      ; BAR;LGKM0;
//        MFMA acc[2..3]; vmcnt(6)
// vmcnt audit (X_t = t-ph0 2 issues [A(t+1,h1)], Y_t = t-ph3 6 issues [A(t+2,h0),
// B(t+2)]): at t-ph3 vmcnt(6) leaves only Y_t outstanding => X_t and Y_{t-1} retired
// => ALL of tile t+1 resident before the BAR that ends tile t. Staged regions are dead
// (their last ds_read completed >=1 barrier earlier). Chunk-XOR swizzle c^(row&7) on
// stage SOURCE and ds_read (both-sides rule).
// Halves are 64 rows; within a half, wr selects 32 rows (2 m-frags); wc selects the
// 64-col B chunk (4 n-frags). 8 MFMA per phase.
//
// Grid is 1-D (nwg % 8 == 0) with XCD-chunked swizzle, x-major so consecutive work ids
// share the B panel (128 x K <= 2.6 MB, fits one XCD's 4MB L2).
template <int IB>
__device__ __forceinline__ void mfma_block(f32x4 (&acc)[4][4], const short8 (&aF)[2],
                                           const short8 (&bF)[4]) {
#pragma unroll
  for (int i = 0; i < 2; ++i)
#pragma unroll
    for (int j = 0; j < 4; ++j)
      acc[IB + i][j] =
          __builtin_amdgcn_mfma_f32_16x16x32_bf16(aF[i], bF[j], acc[IB + i][j], 0, 0, 0);
}

template <int KDIM, int TAPS, int ACT, int OBF16, int PADOUT>
__global__ __launch_bounds__(256)
__attribute__((amdgpu_waves_per_eu(2, 2)))
void gemm128(const u16* __restrict__ A, const u16* __restrict__ Bm,
             const float* __restrict__ bias, void* __restrict__ Cv, int N, int NBX) {
  constexpr int NTK = KDIM / 64;
  constexpr int NT  = NTK * TAPS;
  constexpr int BUFU16 = 16384;                  // 32 KB: A 2x[64][64] + B 2x[64][64]
  __shared__ u16 lds[2][BUFU16];

  // XCD-chunked bijective swizzle (requires gridDim.x % 8 == 0)
  const int cpx = gridDim.x >> 3;
  int lin = blockIdx.x;
  lin = (lin & 7) * cpx + (lin >> 3);
  const int bx = lin % NBX, by = lin / NBX;

  const int tid  = threadIdx.x;
  const int wave = tid >> 6, lane = tid & 63;
  const int wr = wave >> 1, wc = wave & 1;       // 2 x 2 wave grid
  const int q = lane >> 4, r16 = lane & 15;
  const int rsw = r16 & 7;
  const int bm = bx * 128, bn = by * 128;
  const int srow = tid >> 3;                     // 0..31 staging row
  const int schunk = (tid & 7) ^ (srow & 7);     // pre-swizzled source chunk
  const int bbatch = bm >> 11;                   // batch (L_=2048, BM=128 divides)
  const int arow0 = (TAPS == 4) ? (bm + 3 + 6 * bbatch) : bm;

  f32x4 acc[4][4] = {};

  auto stA = [&](int u, int h) {                 // one A half (64 rows): 2 issues
    const int uc = (u < NT) ? u : (NT - 1);
    const int tap = uc / NTK;
    const int ku  = (uc % NTK) * 64;
    const int sh  = (TAPS == 4) ? (2 * tap - 3) : 0;
    const u16* src = A + (size_t)(arow0 + sh + h * 64) * KDIM + ku + schunk * 8;
    u16* dst = &lds[u & 1][h * 4096 + wave * 512];
#pragma unroll
    for (int s = 0; s < 2; ++s)
      gld16(src + (size_t)(s * 32 + srow) * KDIM, dst + s * 2048);
  };
  auto stB = [&](int u, int c) {                 // one B chunk (64 N-rows): 2 issues
    const int uc = (u < NT) ? u : (NT - 1);
    const int tap = uc / NTK;
    const int ku  = (uc % NTK) * 64;
    const u16* src = Bm + (size_t)tap * R_ * R_ +
                     (size_t)(bn + c * 64) * KDIM + ku + schunk * 8;   // r6 fix: no srow here
    u16* dst = &lds[u & 1][8192 + c * 4096 + wave * 512];
#pragma unroll
    for (int s = 0; s < 2; ++s)
      gld16(src + (size_t)(s * 32 + srow) * KDIM, dst + s * 2048);
  };
  auto ldA = [&](short8 (&f)[2], int p, int half, int k) {
    const int base = half * 4096 + (wr * 32 + r16) * 64 + ((k * 4 + q) ^ rsw) * 8;
#pragma unroll
    for (int i = 0; i < 2; ++i)
      f[i] = *(const short8*)&lds[p][base + i * 1024];
  };
  auto ldB = [&](short8 (&f)[4], int p, int k) {
    const int base = 8192 + wc * 4096 + r16 * 64 + ((k * 4 + q) ^ rsw) * 8;
#pragma unroll
    for (int j = 0; j < 4; ++j)
      f[j] = *(const short8*)&lds[p][base + j * 1024];
  };

  // ---- prologue: tile0 fully (8 issues) + tile1's A0 and B (6); A1(1) staged in t=0 ph0
  stA(0, 0); stA(0, 1);
  stB(0, 0); stB(0, 1);
  stA(1, 0);
  stB(1, 0); stB(1, 1);
  asm volatile("s_waitcnt vmcnt(6)" ::: "memory");   // tile0 resident
  SB0();
  BAR();

  short8 aF[2], bF[4];
  for (int t = 0; t < NT; ++t) {
    const int p = t & 1;
    // ---- phase 0: h0 x k0; stage A1(t+1)
    ldA(aF, p, 0, 0);
    ldB(bF, p, 0);
    stA(t + 1, 1);
    BAR(); LGKM0();
    __builtin_amdgcn_s_setprio(1);
    mfma_block<0>(acc, aF, bF);
    __builtin_amdgcn_s_setprio(0);
    SB0(); BAR();
    // ---- phase 1: h1 x k0 (reuses bF)
    ldA(aF, p, 1, 0);
    BAR(); LGKM0();
    __builtin_amdgcn_s_setprio(1);
    mfma_block<2>(acc, aF, bF);
    __builtin_amdgcn_s_setprio(0);
    SB0(); BAR();
    // ---- phase 2: h0 x k1 (reloads bF)
    ldA(aF, p, 0, 1);
    ldB(bF, p, 1);
    BAR(); LGKM0();
    __builtin_amdgcn_s_setprio(1);
    mfma_block<0>(acc, aF, bF);
    __builtin_amdgcn_s_setprio(0);
    SB0(); BAR();
    // ---- phase 3: h1 x k1; stage A0(t+2)+B(t+2) into now-dead regions of lds[p]
    ldA(aF, p, 1, 1);
    stA(t + 2, 0);
    stB(t + 2, 0); stB(t + 2, 1);
    BAR(); LGKM0();
    __builtin_amdgcn_s_setprio(1);
    mfma_block<2>(acc, aF, bF);
    __builtin_amdgcn_s_setprio(0);
    asm volatile("s_waitcnt vmcnt(6)" ::: "memory");
    SB0(); BAR();
  }

  // ---- epilogue
#pragma unroll
  for (int ai = 0; ai < 4; ++ai) {
    const int row = bm + (ai >> 1) * 64 + wr * 32 + (ai & 1) * 16 + q * 4;
    const int orow = PADOUT ? (row + 3 + 6 * bbatch) : row;
#pragma unroll
    for (int j = 0; j < 4; ++j) {
      const int col = bn + wc * 64 + j * 16 + r16;
      const float bv = bias[col];
#pragma unroll
      for (int rr = 0; rr < 4; ++rr) {
        float v = acc[ai][j][rr] + bv;
        if (ACT == 1) v = v / (1.f + __expf(-v));
        const size_t off = (size_t)(orow + rr) * N + col;
        if (OBF16) ((u16*)Cv)[off] = f2bf(v);
        else       ((float*)Cv)[off] = v;
      }
    }
  }
}

// ---------------- RG-LRU gate math (recomputed in both scan passes) ----------------
static __device__ __forceinline__ void gate_math(u16 ga_, u16 gi_, u16 h2_, float sp,
                                                 float& a, float& b) {
  const float ga = bf2f(ga_);
  const float gi = bf2f(gi_);
  const float h2 = bf2f(h2_);
  const float rr = 1.f / (1.f + __expf(-ga));
  const float ii = 1.f / (1.f + __expf(-gi));
  const float log_a = -8.f * rr * sp;
  a = __expf(log_a);
  const float e2 = __expf(2.f * log_a);
  b = sqrtf(fmaxf(1.f - e2, 0.f)) * ii * h2;
}

// ---------------- chunked scan: 3 passes (gate math fused into 1 and 3) ----------------
// gcat: [BL][2R] bf16 (ga | gi), h2b: [BL][R] bf16
__global__ void scan_pass1(const u16* __restrict__ gcat, const u16* __restrict__ h2b,
                           const float* __restrict__ lam,
                           float* __restrict__ Aprod, float* __restrict__ Hend) {
  int t = blockIdx.x * blockDim.x + threadIdx.x;   // over CHK_*B_*R_
  if (t >= CHK_ * B_ * R_) return;
  const int c = t / (B_ * R_), br = t % (B_ * R_);
  const int b = br / R_, r = br % R_;
  const float sp = log1pf(__expf(lam[r]));
  size_t rowbase = (size_t)b * L_ + (size_t)c * CLEN_;
  const u16* pg  = gcat + rowbase * (2 * R_) + r;
  const u16* ph2 = h2b + rowbase * R_ + r;
  float Ap = 1.f, h = 0.f;
  for (int l = 0; l < CLEN_; ++l) {
    float a, bb;
    gate_math(pg[0], pg[R_], ph2[0], sp, a, bb);
    Ap *= a;
    h = a * h + bb;
    pg += 2 * R_;
    ph2 += R_;
  }
  Aprod[t] = Ap;
  Hend[t]  = h;
}

__global__ void scan_pass2(const float* __restrict__ Aprod, float* __restrict__ Hend) {
  int br = blockIdx.x * blockDim.x + threadIdx.x;
  if (br >= B_ * R_) return;
  float h = Hend[br];                               // chunk 0 end state
  for (int c = 1; c < CHK_; ++c) {
    const int i = c * (B_ * R_) + br;
    h = Hend[i] + Aprod[i] * h;
    Hend[i] = h;
  }
}

__global__ void scan_pass3(const u16* __restrict__ gcat, const u16* __restrict__ h2b,
                           const float* __restrict__ lam,
                           const float* __restrict__ Hend, u16* __restrict__ hs) {
  int t = blockIdx.x * blockDim.x + threadIdx.x;
  if (t >= CHK_ * B_ * R_) return;
  const int c = t / (B_ * R_), br = t % (B_ * R_);
  const int b = br / R_, r = br % R_;
  const float sp = log1pf(__expf(lam[r]));
  float h = (c == 0) ? 0.f : Hend[(size_t)(c - 1) * (B_ * R_) + br];
  size_t rowbase = (size_t)b * L_ + (size_t)c * CLEN_;
  const u16* pg  = gcat + rowbase * (2 * R_) + r;
  const u16* ph2 = h2b + rowbase * R_ + r;
  u16* po = hs + rowbase * R_ + r;
  for (int l = 0; l < CLEN_; ++l) {
    float a, bb;
    gate_math(pg[0], pg[R_], ph2[0], sp, a, bb);
    h = a * h + bb;
    *po = f2bf(h);
    pg += 2 * R_;
    ph2 += R_;
    po += R_;
  }
}

// ---------------- launcher ----------------
extern "C" void kernel_launch(void* const* d_in, const int* in_sizes, int n_in,
                              void* d_out, int out_size, void* d_ws, size_t ws_size,
                              hipStream_t stream) {
  (void)in_sizes; (void)n_in; (void)out_size; (void)ws_size;
  const float* x   = (const float*)d_in[0];
  const float* w1  = (const float*)d_in[1];
  const float* b1  = (const float*)d_in[2];
  const float* cw  = (const float*)d_in[3];
  const float* cb  = (const float*)d_in[4];
  const float* wa  = (const float*)d_in[5];
  const float* ba  = (const float*)d_in[6];
  const float* wx  = (const float*)d_in[7];
  const float* bx  = (const float*)d_in[8];
  const float* lam = (const float*)d_in[9];
  const float* w2  = (const float*)d_in[10];
  const float* b2  = (const float*)d_in[11];

  char* ws = (char*)d_ws;
  size_t o = 0;
  auto alloc = [&](size_t bytes) { char* p = ws + o; o += (bytes + 255) & ~255ull; return p; };

  u16* w2b   = (u16*)alloc((size_t)D_ * R_ * 2);
  u16* wcatb = (u16*)alloc((size_t)2 * R_ * R_ * 2);   // [wa ; wx] -> [5120][2560]
  float* bcat = (float*)alloc((size_t)2 * R_ * 4);
  char* hsp = ws + o;                         // overlay: xb+w1b (dead after l1) = 44MB >= 42MB
  u16* xb  = (u16*)alloc((size_t)BL_ * D_ * 2);
  u16* w1b = (u16*)alloc((size_t)R_ * D_ * 2);
  u16* cwb = (u16*)alloc((size_t)4 * R_ * R_ * 2);
  u16* h1p = (u16*)alloc((size_t)B_ * LP_ * R_ * 2);   // padded h1
  u16* h2b = (u16*)alloc((size_t)BL_ * R_ * 2);
  u16* gcat = (u16*)alloc((size_t)BL_ * 2 * R_ * 2);   // [8192][5120] gates
  float* Aprod = (float*)alloc((size_t)CHK_ * B_ * R_ * 4);
  float* Hend  = (float*)alloc((size_t)CHK_ * B_ * R_ * 4);
  u16* hsb = (u16*)hsp;

  cvt_bf16<<<4096, 256, 0, stream>>>(x,  xb,  BL_ * D_);
  cvt_bf16<<<2048, 256, 0, stream>>>(w1, w1b, R_ * D_);
  cvt_bf16<<<2048, 256, 0, stream>>>(wa, wcatb, R_ * R_);
  cvt_bf16<<<2048, 256, 0, stream>>>(wx, wcatb + (size_t)R_ * R_, R_ * R_);
  cvt_bf16<<<2048, 256, 0, stream>>>(w2, w2b, D_ * R_);
  cvt_convw<<<(R_ * R_ + 255) / 256, 256, 0, stream>>>(cw, cwb);
  zero_pads<<<(24 * R_ + 255) / 256, 256, 0, stream>>>(h1p);
  cat_bias<<<(2 * R_ + 255) / 256, 256, 0, stream>>>(ba, bx, bcat);

  // linear1 + silu -> padded h1 (rows +3+6*batch): grid 64 x 20 = 1280
  gemm128<2048, 1, 1, 1, 1><<<1280, 256, 0, stream>>>(xb, w1b, b1, h1p, R_, 64);
  // temporal conv: K' = 4*R GEMM over padded h1: grid 64 x 20 = 1280
  gemm128<2560, 4, 0, 1, 0><<<1280, 256, 0, stream>>>(h1p, cwb, cb, h2b, R_, 64);
  // both gates in ONE GEMM: B = [wa;wx] (5120 x 2560): grid 64 x 40 = 2560 (5x512 exact)
  gemm128<2560, 1, 0, 1, 0><<<2560, 256, 0, stream>>>(h2b, wcatb, bcat, gcat, 2 * R_, 64);
  // linear recurrence (chunked, 3 passes; gate math fused into 1 and 3)
  scan_pass1<<<(CHK_ * B_ * R_ + 255) / 256, 256, 0, stream>>>(gcat, h2b, lam, Aprod, Hend);
  scan_pass2<<<(B_ * R_ + 255) / 256, 256, 0, stream>>>(Aprod, Hend);
  scan_pass3<<<(CHK_ * B_ * R_ + 255) / 256, 256, 0, stream>>>(gcat, h2b, lam, Hend, hsb);
  // linear2 -> d_out (fp32): grid 64 x 16 = 1024 (2x512 exact)
  gemm128<2560, 1, 0, 0, 0><<<1024, 256, 0, stream>>>(hsb, w2b, b2, d_out, D_, 64);
}